// Round 10
// baseline (127.574 us; speedup 1.0000x reference)
//
#include <hip/hip_runtime.h>

#define BD 16
#define EMBD 128
#define H0D 256
#define UPD 512
#define RAD 60
#define PATCHD 120
#define COEFF 1.5f
#define NB 256          // partial-reduction blocks per batch
#define CHUNK 1024      // pixels per partial block (2 rows of 512)
#define SKIPR 32.0f     // 24 (disk) + 8 margin (bilinear/floor reach <= ~3.5)

// ---------------- small helpers ----------------

__device__ __forceinline__ float bsample(const float* __restrict__ img, int H, int W,
                                         float gx, float gy) {
    float xs = ((gx + 1.f) * (float)W - 1.f) * 0.5f;
    float ys = ((gy + 1.f) * (float)H - 1.f) * 0.5f;
    float x0f = floorf(xs), y0f = floorf(ys);
    float wx = xs - x0f, wy = ys - y0f;
    int x0 = (int)x0f, y0 = (int)y0f;
    bool vx0 = (x0 >= 0) && (x0 <= W - 1);
    bool vx1 = (x0 + 1 >= 0) && (x0 + 1 <= W - 1);
    bool vy0 = (y0 >= 0) && (y0 <= H - 1);
    bool vy1 = (y0 + 1 >= 0) && (y0 + 1 <= H - 1);
    int xi0 = min(max(x0, 0), W - 1);
    int xi1 = min(max(x0 + 1, 0), W - 1);
    int yi0 = min(max(y0, 0), H - 1);
    int yi1 = min(max(y0 + 1, 0), H - 1);
    float v00 = (vy0 && vx0) ? img[yi0 * W + xi0] : 0.f;
    float v01 = (vy0 && vx1) ? img[yi0 * W + xi1] : 0.f;
    float v10 = (vy1 && vx0) ? img[yi1 * W + xi0] : 0.f;
    float v11 = (vy1 && vx1) ? img[yi1 * W + xi1] : 0.f;
    return v00 * (1.f - wy) * (1.f - wx) + v01 * (1.f - wy) * wx +
           v10 * wy * (1.f - wx) + v11 * wy * wx;
}

// ---------------- kernels ----------------

// gemm (blocks 0..255) + affine inversions (block 256)
__global__ __launch_bounds__(256) void k_gemm(const float* __restrict__ kout,
                                              const float* __restrict__ Wd,
                                              float* __restrict__ base,
                                              const float* __restrict__ ss,
                                              const float* __restrict__ rot,
                                              float* __restrict__ invbuf) {
    if (blockIdx.x == 256) {
        int b = threadIdx.x;
        if (b < BD) {
            {
                const float* A = ss + b * 6;
                float a = A[0], bb = A[1], c = A[3], d = A[4];
                float det = a * d - bb * c;
                float* o = invbuf + b * 6;
                o[0] = d / det; o[1] = -bb / det; o[2] = 0.f;
                o[3] = -c / det; o[4] = a / det; o[5] = 0.f;
            }
            {
                const float* A = rot + b * 6;
                float a = A[0], bb = A[1], c = A[3], d = A[4];
                float det = a * d - bb * c;
                float* o = invbuf + 96 + b * 6;
                o[0] = d / det; o[1] = -bb / det; o[2] = 0.f;
                o[3] = -c / det; o[4] = a / det; o[5] = 0.f;
            }
        }
        return;
    }
    __shared__ float sk[BD * EMBD];
    int t = threadIdx.x;
    for (int i = t; i < BD * EMBD; i += 256) sk[i] = kout[i];
    __syncthreads();
    int n = blockIdx.x * 256 + t;
    float acc[BD];
#pragma unroll
    for (int b = 0; b < BD; b++) acc[b] = 0.f;
    for (int e = 0; e < EMBD; e++) {
        float w = Wd[(size_t)e * (H0D * H0D) + n];
#pragma unroll
        for (int b = 0; b < BD; b++) acc[b] += sk[b * EMBD + e] * w;
    }
#pragma unroll
    for (int b = 0; b < BD; b++)
        base[(size_t)b * (H0D * H0D) + n] = fmaxf(acc[b], 0.f);
}

// resize (blocks 0..BD*NB-1) || mask-pack (next 1024) || x-copy (next 1024)
__global__ __launch_bounds__(256) void k_stage(
        const float* __restrict__ base, float* __restrict__ out_base,
        const float* __restrict__ masks, float4* __restrict__ packed,
        const float* __restrict__ x, float* __restrict__ out_x) {
    int g = blockIdx.x;
    int t = threadIdx.x;
    if (g < BD * NB) {
        int b = g & (BD - 1);
        int blk = g >> 4;
        const float* img = base + (size_t)b * (H0D * H0D);
        float* ob = out_base + (size_t)b * (UPD * UPD);
        int p0 = blk * CHUNK + t * 4;
        float4 o;
        float* op = (float*)&o;
#pragma unroll
        for (int u = 0; u < 4; u++) {
            int p = p0 + u;
            int yo = p >> 9, xo = p & 511;
            float ysf = fminf(fmaxf(((float)yo + 0.5f) * 0.5f - 0.5f, 0.f), 255.f);
            float xsf = fminf(fmaxf(((float)xo + 0.5f) * 0.5f - 0.5f, 0.f), 255.f);
            int y0 = (int)floorf(ysf), x0 = (int)floorf(xsf);
            int y1 = min(y0 + 1, H0D - 1), x1 = min(x0 + 1, H0D - 1);
            float wy = ysf - (float)y0, wx = xsf - (float)x0;
            float Ia = img[y0 * H0D + x0], Ib = img[y0 * H0D + x1];
            float Ic = img[y1 * H0D + x0], Id = img[y1 * H0D + x1];
            op[u] = Ia * (1.f - wy) * (1.f - wx) + Ib * (1.f - wy) * wx +
                    Ic * wy * (1.f - wx) + Id * wy * wx;
        }
        *(float4*)(ob + p0) = o;
    } else if (g < BD * NB + 1024) {
        int p = (g - BD * NB) * 256 + t;
        float4 v;
        v.x = masks[p];
        v.y = masks[(size_t)(UPD * UPD) + p];
        v.z = masks[(size_t)2 * (UPD * UPD) + p];
        v.w = masks[(size_t)3 * (UPD * UPD) + p];
        packed[p] = v;
    } else {
        int idx = (g - BD * NB - 1024) * 256 + t;
        ((float4*)out_x)[idx] = ((const float4*)x)[idx];
    }
}

// affine grid-sample, batch-interleaved, 4 pixels/thread with float4 store
__global__ __launch_bounds__(256) void k_sample(const float* __restrict__ in,
                                                const float* __restrict__ theta,
                                                float* __restrict__ out) {
    int g = blockIdx.x;
    int b = g & (BD - 1);
    int blk = g >> 4;
    int t = threadIdx.x;
    const float* th = theta + b * 6;
    float a0 = th[0], a1 = th[1], a2 = th[2];
    float a3 = th[3], a4 = th[4], a5 = th[5];
    const float* img = in + (size_t)b * (UPD * UPD);
    float* ob = out + (size_t)b * (UPD * UPD);
    int p0 = blk * CHUNK + t * 4;
    float4 o;
    float* op = (float*)&o;
#pragma unroll
    for (int u = 0; u < 4; u++) {
        int p = p0 + u;
        int yo = p >> 9, xo = p & 511;
        float X = ((float)xo + 0.5f) * (2.f / UPD) - 1.f;
        float Y = ((float)yo + 0.5f) * (2.f / UPD) - 1.f;
        float gx = a0 * X + a1 * Y + a2;
        float gy = a3 * X + a4 * Y + a5;
        op[u] = bsample(img, UPD, UPD, gx, gy);
    }
    *(float4*)(ob + p0) = o;
}

// FUSED: pred_in = sample(pred_rot, inv1) written to out_img, PLUS
// rm_j = (sample(sample(mask_j, inv2), inv1) >= 0.5) + stats pass 1.
// Strip-skip AND per-pixel composite-distance cull. 4 px/thread, vector stores.
__global__ __launch_bounds__(256) void k_predmask(
        const float* __restrict__ pred_rot, const float4* __restrict__ packed,
        const float* __restrict__ invbuf, float* __restrict__ out_img,
        uchar4* __restrict__ rm, float* __restrict__ part1,
        unsigned int* __restrict__ flags) {
    int g = blockIdx.x;
    int b = g & (BD - 1);
    int blk = g >> 4;
    int t = threadIdx.x;
    const float* th1 = invbuf + b * 6;        // outer (inv1)
    const float* th2 = invbuf + 96 + b * 6;   // inner (inv2)
    float a10 = th1[0], a11 = th1[1], a12 = th1[2];
    float a13 = th1[3], a14 = th1[4], a15 = th1[5];
    float a20 = th2[0], a21 = th2[1], a22 = th2[2];
    float a23 = th2[3], a24 = th2[4], a25 = th2[5];

    __shared__ unsigned int sflag;
    if (t == 0) {
        const float crow[4] = {160.f, 160.f, 352.f, 352.f};
        const float ccol[4] = {160.f, 352.f, 160.f, 352.f};
        unsigned int f = 0;
        int r0 = blk * 2;
        for (int rr = 0; rr < 2; rr++) {
            float Y = ((float)(r0 + rr) + 0.5f) * (2.f / UPD) - 1.f;
            float X0 = 0.5f * (2.f / UPD) - 1.f;
            float X1 = 511.5f * (2.f / UPD) - 1.f;
            float gx0 = a10 * X0 + a11 * Y + a12, gy0 = a13 * X0 + a14 * Y + a15;
            float gx1 = a10 * X1 + a11 * Y + a12, gy1 = a13 * X1 + a14 * Y + a15;
            float c0 = 256.f * (a20 * gx0 + a21 * gy0 + a22) + 255.5f;
            float w0 = 256.f * (a23 * gx0 + a24 * gy0 + a25) + 255.5f;
            float c1 = 256.f * (a20 * gx1 + a21 * gy1 + a22) + 255.5f;
            float w1 = 256.f * (a23 * gx1 + a24 * gy1 + a25) + 255.5f;
            float vx = c1 - c0, vy = w1 - w0;
            float vv = fmaxf(vx * vx + vy * vy, 1e-12f);
            for (int j = 0; j < 4; j++) {
                float ux = c0 - ccol[j], uy = w0 - crow[j];
                float tt = fminf(fmaxf(-(ux * vx + uy * vy) / vv, 0.f), 1.f);
                float dx = ux + tt * vx, dy = uy + tt * vy;
                if (dx * dx + dy * dy <= SKIPR * SKIPR) f |= (1u << j);
            }
        }
        sflag = f;
        flags[b * NB + blk] = f;
        if (f == 0) {
#pragma unroll
            for (int j = 0; j < 4; j++) {
                part1[((size_t)(j * BD + b) * NB + blk) * 2 + 0] = 0.f;
                part1[((size_t)(j * BD + b) * NB + blk) * 2 + 1] = 0.f;
            }
        }
    }
    __syncthreads();
    unsigned int f = sflag;

    const float* pr = pred_rot + (size_t)b * (UPD * UPD);
    float* oi = out_img + (size_t)b * (UPD * UPD);
    uchar4* rmb = rm + (size_t)b * (UPD * UPD);
    float s_new[4] = {0.f, 0.f, 0.f, 0.f};
    float s_m[4] = {0.f, 0.f, 0.f, 0.f};
    int p0 = blk * CHUNK + t * 4;
    float4 ov4;
    float* ovp = (float*)&ov4;
    unsigned int rmw[4];
#pragma unroll
    for (int u = 0; u < 4; u++) {
        int p = p0 + u;
        int yo = p >> 9, xo = p & 511;
        float X = ((float)xo + 0.5f) * (2.f / UPD) - 1.f;
        float Y = ((float)yo + 0.5f) * (2.f / UPD) - 1.f;
        float gx = a10 * X + a11 * Y + a12;
        float gy = a13 * X + a14 * Y + a15;
        float xs = ((gx + 1.f) * (float)UPD - 1.f) * 0.5f;
        float ys = ((gy + 1.f) * (float)UPD - 1.f) * 0.5f;
        float x0f = floorf(xs), y0f = floorf(ys);
        float wx = xs - x0f, wy = ys - y0f;
        int x0 = (int)x0f, y0 = (int)y0f;
        // per-pixel cull via composite affine distance to the 4 disk centers
        bool pact = false;
        if (f) {
            float cxp = 256.f * (a20 * gx + a21 * gy + a22) + 255.5f;
            float cwp = 256.f * (a23 * gx + a24 * gy + a25) + 255.5f;
            const float crow[4] = {160.f, 160.f, 352.f, 352.f};
            const float ccol[4] = {160.f, 352.f, 160.f, 352.f};
#pragma unroll
            for (int j = 0; j < 4; j++) {
                float dx = cxp - ccol[j], dy = cwp - crow[j];
                if (dx * dx + dy * dy <= SKIPR * SKIPR) pact = true;
            }
        }
        float piv = 0.f;
        float m0 = 0.f, m1 = 0.f, m2 = 0.f, m3 = 0.f;
#pragma unroll
        for (int q = 0; q < 4; q++) {
            int qy = y0 + (q >> 1), qx = x0 + (q & 1);
            bool qv = (qx >= 0) && (qx < UPD) && (qy >= 0) && (qy < UPD);
            float fy = (q >> 1) ? wy : (1.f - wy);
            float fx = (q & 1) ? wx : (1.f - wx);
            if (qv) {
                piv += pr[qy * UPD + qx] * fy * fx;
                if (pact) {
                    float Xq = ((float)qx + 0.5f) * (2.f / UPD) - 1.f;
                    float Yq = ((float)qy + 0.5f) * (2.f / UPD) - 1.f;
                    float g2x = a20 * Xq + a21 * Yq + a22;
                    float g2y = a23 * Xq + a24 * Yq + a25;
                    float xs2 = ((g2x + 1.f) * (float)UPD - 1.f) * 0.5f;
                    float ys2 = ((g2y + 1.f) * (float)UPD - 1.f) * 0.5f;
                    float x0f2 = floorf(xs2), y0f2 = floorf(ys2);
                    float wx2 = xs2 - x0f2, wy2 = ys2 - y0f2;
                    int x02 = (int)x0f2, y02 = (int)y0f2;
                    bool vx0 = (x02 >= 0) && (x02 <= UPD - 1);
                    bool vx1 = (x02 + 1 >= 0) && (x02 + 1 <= UPD - 1);
                    bool vy0 = (y02 >= 0) && (y02 <= UPD - 1);
                    bool vy1 = (y02 + 1 >= 0) && (y02 + 1 <= UPD - 1);
                    int xi0 = min(max(x02, 0), UPD - 1);
                    int xi1 = min(max(x02 + 1, 0), UPD - 1);
                    int yi0 = min(max(y02, 0), UPD - 1);
                    int yi1 = min(max(y02 + 1, 0), UPD - 1);
                    float4 c00 = packed[yi0 * UPD + xi0];
                    float4 c01 = packed[yi0 * UPD + xi1];
                    float4 c10 = packed[yi1 * UPD + xi0];
                    float4 c11 = packed[yi1 * UPD + xi1];
                    const float* f00 = (const float*)&c00;
                    const float* f01 = (const float*)&c01;
                    const float* f10 = (const float*)&c10;
                    const float* f11 = (const float*)&c11;
                    float rq[4];
#pragma unroll
                    for (int j = 0; j < 4; j++) {
                        float v00 = (vy0 && vx0) ? f00[j] : 0.f;
                        float v01 = (vy0 && vx1) ? f01[j] : 0.f;
                        float v10 = (vy1 && vx0) ? f10[j] : 0.f;
                        float v11 = (vy1 && vx1) ? f11[j] : 0.f;
                        rq[j] = v00 * (1.f - wy2) * (1.f - wx2) +
                                v01 * (1.f - wy2) * wx2 +
                                v10 * wy2 * (1.f - wx2) + v11 * wy2 * wx2;
                    }
                    m0 += rq[0] * fy * fx;
                    m1 += rq[1] * fy * fx;
                    m2 += rq[2] * fy * fx;
                    m3 += rq[3] * fy * fx;
                }
            }
        }
        ovp[u] = piv;
        rmw[u] = 0u;
        if (f) {
            uchar4 rmv;
            unsigned char* rmc = (unsigned char*)&rmv;
            float mj[4] = {m0, m1, m2, m3};
#pragma unroll
            for (int j = 0; j < 4; j++) {
                float mm = (mj[j] >= 0.5f) ? 1.f : 0.f;
                rmc[j] = (unsigned char)mm;
                s_new[j] += piv * mm;
                s_m[j] += mm;
            }
            __builtin_memcpy(&rmw[u], &rmv, 4);
        }
    }
    *(float4*)(oi + p0) = ov4;
    if (f) {
        uint4 w4;
        w4.x = rmw[0]; w4.y = rmw[1]; w4.z = rmw[2]; w4.w = rmw[3];
        *(uint4*)(rmb + p0) = w4;
    }
    if (f) {
        __shared__ float r1[256], r2[256];
        for (int j = 0; j < 4; j++) {
            r1[t] = s_new[j];
            r2[t] = s_m[j];
            __syncthreads();
            for (int s = 128; s > 0; s >>= 1) {
                if (t < s) { r1[t] += r1[t + s]; r2[t] += r2[t + s]; }
                __syncthreads();
            }
            if (t == 0) {
                part1[((size_t)(j * BD + b) * NB + blk) * 2 + 0] = r1[0];
                part1[((size_t)(j * BD + b) * NB + blk) * 2 + 1] = r2[0];
            }
            __syncthreads();
        }
    }
}

// All 4 j: thr (redundant reduce of part1) + centroid partials; strip-skip via
// flags; one 4-px uint4 group per thread.
__global__ __launch_bounds__(256) void k_maskB(
        const float* __restrict__ pred_in, const uchar4* __restrict__ rm,
        const float* __restrict__ part1, float* __restrict__ part2,
        const unsigned int* __restrict__ flags) {
    int g = blockIdx.x;
    int b = g & (BD - 1);
    int blk = g >> 4;
    int t = threadIdx.x;
    unsigned int flag = flags[b * NB + blk];
    if (flag == 0) {
        if (t == 0) {
#pragma unroll
            for (int j = 0; j < 4; j++) {
                float* o = part2 + ((size_t)(j * BD + b) * NB + blk) * 4;
                o[0] = 0.f; o[1] = 0.f; o[2] = 0.f;
            }
        }
        return;
    }
    __shared__ float r1[256], r2[256], r3[256];
    float thr[4];
    for (int j = 0; j < 4; j++) {
        r1[t] = part1[((size_t)(j * BD + b) * NB + t) * 2 + 0];
        r2[t] = part1[((size_t)(j * BD + b) * NB + t) * 2 + 1];
        __syncthreads();
        for (int s = 128; s > 0; s >>= 1) {
            if (t < s) { r1[t] += r1[t + s]; r2[t] += r2[t + s]; }
            __syncthreads();
        }
        thr[j] = COEFF * (r1[0] / fmaxf(r2[0], 1.f));
        __syncthreads();
    }
    float tot[4] = {0.f, 0.f, 0.f, 0.f};
    float sx[4] = {0.f, 0.f, 0.f, 0.f};
    float sy[4] = {0.f, 0.f, 0.f, 0.f};
    const float* pi = pred_in + (size_t)b * (UPD * UPD);
    const uchar4* rmb = rm + (size_t)b * (UPD * UPD);
    int p0 = blk * CHUNK + t * 4;
    uint4 mw = *(const uint4*)(rmb + p0);
    if ((mw.x | mw.y | mw.z | mw.w) != 0) {
        float4 pv4 = *(const float4*)(pi + p0);
        const float* pvp = (const float*)&pv4;
        unsigned int mwa[4] = {mw.x, mw.y, mw.z, mw.w};
#pragma unroll
        for (int u = 0; u < 4; u++) {
            if (mwa[u] == 0) continue;
            int p = p0 + u;
            float piv = pvp[u];
            float fi = (float)(p >> 9), fj = (float)(p & 511);
            const unsigned char* mmc = (const unsigned char*)&mwa[u];
#pragma unroll
            for (int j = 0; j < 4; j++) {
                float mm = (float)mmc[j];
                float ni = piv * mm;
                bool sel = (mm > 0.f) && (ni > thr[j]);
                float w = sel ? ni : 0.f;
                tot[j] += w;
                sx[j] += w * fi;
                sy[j] += w * fj;
            }
        }
    }
    for (int j = 0; j < 4; j++) {
        r1[t] = tot[j]; r2[t] = sx[j]; r3[t] = sy[j];
        __syncthreads();
        for (int s = 128; s > 0; s >>= 1) {
            if (t < s) { r1[t] += r1[t + s]; r2[t] += r2[t + s]; r3[t] += r3[t + s]; }
            __syncthreads();
        }
        if (t == 0) {
            float* o = part2 + ((size_t)(j * BD + b) * NB + blk) * 4;
            o[0] = r1[0]; o[1] = r2[0]; o[2] = r3[0];
        }
        __syncthreads();
    }
}

// shared centroid finalize (redundant deterministic reduce per block)
#define CENT_REDUCE(part2, b, t, cs)                                             \
    {                                                                            \
        __shared__ float r1[256], r2[256], r3[256];                              \
        for (int j = 0; j < 4; j++) {                                            \
            if (t < 256) {                                                       \
                const float* pp2 = part2 + ((size_t)(j * BD + b) * NB + t) * 4;  \
                r1[t] = pp2[0]; r2[t] = pp2[1]; r3[t] = pp2[2];                  \
            }                                                                    \
            __syncthreads();                                                     \
            for (int s = 128; s > 0; s >>= 1) {                                  \
                if (t < s) {                                                     \
                    r1[t] += r1[t + s]; r2[t] += r2[t + s]; r3[t] += r3[t + s];  \
                }                                                                \
                __syncthreads();                                                 \
            }                                                                    \
            if (t == 0) {                                                        \
                float tot_ = r1[0] + 1e-8f;                                      \
                float cx_ = r2[0] / tot_;                                        \
                float cy_ = r3[0] / tot_;                                        \
                cs[j * 2 + 0] =                                                  \
                    (int)fminf(fmaxf(rintf(cx_), (float)RAD), (float)(UPD - RAD));\
                cs[j * 2 + 1] =                                                  \
                    (int)fminf(fmaxf(rintf(cy_), (float)RAD), (float)(UPD - RAD));\
            }                                                                    \
            __syncthreads();                                                     \
        }                                                                        \
        if (t == 0) {                                                            \
            int ov_ = 0;                                                         \
            for (int a_ = 0; a_ < 4; a_++)                                       \
                for (int c_ = a_ + 1; c_ < 4; c_++) {                            \
                    int dr = cs[a_ * 2] - cs[c_ * 2];                            \
                    int dc = cs[a_ * 2 + 1] - cs[c_ * 2 + 1];                    \
                    if (dr < 0) dr = -dr;                                        \
                    if (dc < 0) dc = -dc;                                        \
                    if (dr < 2 * RAD && dc < 2 * RAD) ov_ = 1;                   \
                }                                                                \
            cs[8] = ov_;                                                         \
        }                                                                        \
        __syncthreads();                                                         \
    }

// 64 blocks = (b, j). Disjoint case: block (b,j) does LDS-staged
// extract -> resample -> write-back on its own (disjoint) region.
// Overlap case: block (b,0) does the exact sequential 4-step path.
__global__ __launch_bounds__(1024) void k_revise(
        const float* __restrict__ part2, const float* __restrict__ invbuf,
        const float* __restrict__ adj, float* __restrict__ img) {
    int b = blockIdx.x >> 2;
    int jown = blockIdx.x & 3;
    int t = threadIdx.x;
    __shared__ int cs[9];
    CENT_REDUCE(part2, b, t, cs);
    const float* th = invbuf + b * 6;  // inv1
    float th0 = th[0], th1v = th[1], th2v = th[2];
    float th3v = th[3], th4v = th[4], th5v = th[5];
    float a = adj[b];
    float* im = img + (size_t)b * (UPD * UPD);
    __shared__ float patch[PATCHD * PATCHD];
    int jlo = jown, jhi = jown + 1;
    if (cs[8]) {
        if (jown != 0) return;
        jlo = 0; jhi = 4;
    }
    for (int j = jlo; j < jhi; j++) {
        int cxi = cs[j * 2 + 0], cyi = cs[j * 2 + 1];
        for (int p = t; p < PATCHD * PATCHD; p += 1024) {
            int i = p / PATCHD, jj = p - i * PATCHD;
            float v = im[(cxi - RAD + i) * UPD + (cyi - RAD + jj)];
            int di = i - RAD, dj = jj - RAD;
            if (di * di + dj * dj <= 100) v /= a;  // _DOT = 10
            patch[p] = v;
        }
        __syncthreads();
        for (int p = t; p < PATCHD * PATCHD; p += 1024) {
            int i = p / PATCHD, jj = p - i * PATCHD;
            float X = ((float)jj + 0.5f) * (2.f / PATCHD) - 1.f;
            float Y = ((float)i + 0.5f) * (2.f / PATCHD) - 1.f;
            float gx = th0 * X + th1v * Y + th2v;
            float gy = th3v * X + th4v * Y + th5v;
            float v = bsample(patch, PATCHD, PATCHD, gx, gy);
            im[(cxi - RAD + i) * UPD + (cyi - RAD + jj)] = v;
        }
        __syncthreads();
    }
}

// ---------------- launch ----------------

extern "C" void kernel_launch(void* const* d_in, const int* in_sizes, int n_in,
                              void* d_out, int out_size, void* d_ws, size_t ws_size,
                              hipStream_t stream) {
    const float* x = (const float*)d_in[0];
    const float* k_out = (const float*)d_in[1];
    const float* W_dec = (const float*)d_in[2];
    const float* ss = (const float*)d_in[3];
    const float* rot = (const float*)d_in[4];
    const float* masks = (const float*)d_in[5];
    const float* adj = (const float*)d_in[6];

    float* out = (float*)d_out;
    const size_t NX = (size_t)BD * H0D * H0D;      // 1,048,576
    const size_t P = (size_t)BD * UPD * UPD;       // 4,194,304
    float* out_x = out;
    float* out_base = out + NX;
    float* out_img = out + NX + P;                 // pred_in lives here (pristine
                                                   // until k_revise patches it)

    float* ws = (float*)d_ws;
    float* slotR = ws;                   // pred_rot              (P floats)
    uchar4* rm = (uchar4*)(ws + P);      // BD*512*512 uchar4     (P bytes)
    float* slotC = ws + 2 * P;           // base (P/4 floats)
    float* invbuf = ws + 2 * P + P / 4;  // 192 floats
    float* part1 = invbuf + 192;                  // 4*16*256*2 floats
    float* part2 = part1 + 4 * BD * NB * 2;       // 4*16*256*4 floats
    unsigned int* flags = (unsigned int*)(part2 + 4 * BD * NB * 4);  // 16*256 uints
    float4* packed = (float4*)((float*)(flags + BD * NB));  // 512*512 float4 = 4MB

    float* inv2 = invbuf + 96;

    // gemm + affine inversions
    k_gemm<<<257, 256, 0, stream>>>(k_out, W_dec, slotC, ss, rot, invbuf);
    // resize || mask-pack || x-copy
    k_stage<<<BD * NB + 2048, 256, 0, stream>>>(slotC, out_base, masks, packed,
                                                x, out_x);
    // pred_rot = sample(base_inp, inv2)
    k_sample<<<BD * NB, 256, 0, stream>>>(out_base, inv2, slotR);
    // pred_in (out_img) + all-4-mask double-sample + stats pass 1, fused
    k_predmask<<<BD * NB, 256, 0, stream>>>(slotR, packed, invbuf, out_img, rm,
                                            part1, flags);
    // all 4 masks: thr + centroid partials
    k_maskB<<<BD * NB, 256, 0, stream>>>(out_img, rm, part1, part2, flags);
    // centroids + revise, parallel over (b, j) with sequential fallback
    k_revise<<<BD * 4, 1024, 0, stream>>>(part2, invbuf, adj, out_img);
}

// Round 11
// 113.696 us; speedup vs baseline: 1.1221x; 1.1221x over previous
//
#include <hip/hip_runtime.h>

#define BD 16
#define EMBD 128
#define H0D 256
#define UPD 512
#define RAD 60
#define PATCHD 120
#define COEFF 1.5f
#define NB 256          // partial-reduction blocks per batch
#define CHUNK 1024      // pixels per partial block (2 rows of 512)
#define SKIPR 32.0f     // 24 (disk) + 8 margin (bilinear/floor reach <= ~3.5)

// ---------------- small helpers ----------------

__device__ __forceinline__ float bsample(const float* __restrict__ img, int H, int W,
                                         float gx, float gy) {
    float xs = ((gx + 1.f) * (float)W - 1.f) * 0.5f;
    float ys = ((gy + 1.f) * (float)H - 1.f) * 0.5f;
    float x0f = floorf(xs), y0f = floorf(ys);
    float wx = xs - x0f, wy = ys - y0f;
    int x0 = (int)x0f, y0 = (int)y0f;
    bool vx0 = (x0 >= 0) && (x0 <= W - 1);
    bool vx1 = (x0 + 1 >= 0) && (x0 + 1 <= W - 1);
    bool vy0 = (y0 >= 0) && (y0 <= H - 1);
    bool vy1 = (y0 + 1 >= 0) && (y0 + 1 <= H - 1);
    int xi0 = min(max(x0, 0), W - 1);
    int xi1 = min(max(x0 + 1, 0), W - 1);
    int yi0 = min(max(y0, 0), H - 1);
    int yi1 = min(max(y0 + 1, 0), H - 1);
    float v00 = (vy0 && vx0) ? img[yi0 * W + xi0] : 0.f;
    float v01 = (vy0 && vx1) ? img[yi0 * W + xi1] : 0.f;
    float v10 = (vy1 && vx0) ? img[yi1 * W + xi0] : 0.f;
    float v11 = (vy1 && vx1) ? img[yi1 * W + xi1] : 0.f;
    return v00 * (1.f - wy) * (1.f - wx) + v01 * (1.f - wy) * wx +
           v10 * wy * (1.f - wx) + v11 * wy * wx;
}

// ---------------- kernels ----------------

// gemm (blocks 0..255) + affine inversions (block 256)
__global__ __launch_bounds__(256) void k_gemm(const float* __restrict__ kout,
                                              const float* __restrict__ Wd,
                                              float* __restrict__ base,
                                              const float* __restrict__ ss,
                                              const float* __restrict__ rot,
                                              float* __restrict__ invbuf) {
    if (blockIdx.x == 256) {
        int b = threadIdx.x;
        if (b < BD) {
            {
                const float* A = ss + b * 6;
                float a = A[0], bb = A[1], c = A[3], d = A[4];
                float det = a * d - bb * c;
                float* o = invbuf + b * 6;
                o[0] = d / det; o[1] = -bb / det; o[2] = 0.f;
                o[3] = -c / det; o[4] = a / det; o[5] = 0.f;
            }
            {
                const float* A = rot + b * 6;
                float a = A[0], bb = A[1], c = A[3], d = A[4];
                float det = a * d - bb * c;
                float* o = invbuf + 96 + b * 6;
                o[0] = d / det; o[1] = -bb / det; o[2] = 0.f;
                o[3] = -c / det; o[4] = a / det; o[5] = 0.f;
            }
        }
        return;
    }
    __shared__ float sk[BD * EMBD];
    int t = threadIdx.x;
    for (int i = t; i < BD * EMBD; i += 256) sk[i] = kout[i];
    __syncthreads();
    int n = blockIdx.x * 256 + t;
    float acc[BD];
#pragma unroll
    for (int b = 0; b < BD; b++) acc[b] = 0.f;
    for (int e = 0; e < EMBD; e++) {
        float w = Wd[(size_t)e * (H0D * H0D) + n];
#pragma unroll
        for (int b = 0; b < BD; b++) acc[b] += sk[b * EMBD + e] * w;
    }
#pragma unroll
    for (int b = 0; b < BD; b++)
        base[(size_t)b * (H0D * H0D) + n] = fmaxf(acc[b], 0.f);
}

// resize (blocks 0..BD*NB-1) || mask-pack (next 1024) || x-copy (next 1024)
__global__ __launch_bounds__(256) void k_stage(
        const float* __restrict__ base, float* __restrict__ out_base,
        const float* __restrict__ masks, float4* __restrict__ packed,
        const float* __restrict__ x, float* __restrict__ out_x) {
    int g = blockIdx.x;
    int t = threadIdx.x;
    if (g < BD * NB) {
        int b = g & (BD - 1);
        int blk = g >> 4;
        const float* img = base + (size_t)b * (H0D * H0D);
        float* ob = out_base + (size_t)b * (UPD * UPD);
        int p0 = blk * CHUNK + t * 4;
        float4 o;
        float* op = (float*)&o;
#pragma unroll
        for (int u = 0; u < 4; u++) {
            int p = p0 + u;
            int yo = p >> 9, xo = p & 511;
            float ysf = fminf(fmaxf(((float)yo + 0.5f) * 0.5f - 0.5f, 0.f), 255.f);
            float xsf = fminf(fmaxf(((float)xo + 0.5f) * 0.5f - 0.5f, 0.f), 255.f);
            int y0 = (int)floorf(ysf), x0 = (int)floorf(xsf);
            int y1 = min(y0 + 1, H0D - 1), x1 = min(x0 + 1, H0D - 1);
            float wy = ysf - (float)y0, wx = xsf - (float)x0;
            float Ia = img[y0 * H0D + x0], Ib = img[y0 * H0D + x1];
            float Ic = img[y1 * H0D + x0], Id = img[y1 * H0D + x1];
            op[u] = Ia * (1.f - wy) * (1.f - wx) + Ib * (1.f - wy) * wx +
                    Ic * wy * (1.f - wx) + Id * wy * wx;
        }
        *(float4*)(ob + p0) = o;
    } else if (g < BD * NB + 1024) {
        int p = (g - BD * NB) * 256 + t;
        float4 v;
        v.x = masks[p];
        v.y = masks[(size_t)(UPD * UPD) + p];
        v.z = masks[(size_t)2 * (UPD * UPD) + p];
        v.w = masks[(size_t)3 * (UPD * UPD) + p];
        packed[p] = v;
    } else {
        int idx = (g - BD * NB - 1024) * 256 + t;
        ((float4*)out_x)[idx] = ((const float4*)x)[idx];
    }
}

// affine grid-sample, batch-interleaved, 4 pixels/thread with float4 store
__global__ __launch_bounds__(256) void k_sample(const float* __restrict__ in,
                                                const float* __restrict__ theta,
                                                float* __restrict__ out) {
    int g = blockIdx.x;
    int b = g & (BD - 1);
    int blk = g >> 4;
    int t = threadIdx.x;
    const float* th = theta + b * 6;
    float a0 = th[0], a1 = th[1], a2 = th[2];
    float a3 = th[3], a4 = th[4], a5 = th[5];
    const float* img = in + (size_t)b * (UPD * UPD);
    float* ob = out + (size_t)b * (UPD * UPD);
    int p0 = blk * CHUNK + t * 4;
    float4 o;
    float* op = (float*)&o;
#pragma unroll
    for (int u = 0; u < 4; u++) {
        int p = p0 + u;
        int yo = p >> 9, xo = p & 511;
        float X = ((float)xo + 0.5f) * (2.f / UPD) - 1.f;
        float Y = ((float)yo + 0.5f) * (2.f / UPD) - 1.f;
        float gx = a0 * X + a1 * Y + a2;
        float gy = a3 * X + a4 * Y + a5;
        op[u] = bsample(img, UPD, UPD, gx, gy);
    }
    *(float4*)(ob + p0) = o;
}

// FUSED: pred_in = sample(pred_rot, inv1) written to out_img, PLUS
// rm_j = (sample(sample(mask_j, inv2), inv1) >= 0.5) + stats pass 1.
// Strip-skip AND per-pixel composite-distance cull. Lane-adjacent 1 px/thread
// per iteration (gather-coalescing-friendly; reverted from 4px/thread).
__global__ __launch_bounds__(256) void k_predmask(
        const float* __restrict__ pred_rot, const float4* __restrict__ packed,
        const float* __restrict__ invbuf, float* __restrict__ out_img,
        uchar4* __restrict__ rm, float* __restrict__ part1,
        unsigned int* __restrict__ flags) {
    int g = blockIdx.x;
    int b = g & (BD - 1);
    int blk = g >> 4;
    int t = threadIdx.x;
    const float* th1 = invbuf + b * 6;        // outer (inv1)
    const float* th2 = invbuf + 96 + b * 6;   // inner (inv2)
    float a10 = th1[0], a11 = th1[1], a12 = th1[2];
    float a13 = th1[3], a14 = th1[4], a15 = th1[5];
    float a20 = th2[0], a21 = th2[1], a22 = th2[2];
    float a23 = th2[3], a24 = th2[4], a25 = th2[5];

    __shared__ unsigned int sflag;
    if (t == 0) {
        const float crow[4] = {160.f, 160.f, 352.f, 352.f};
        const float ccol[4] = {160.f, 352.f, 160.f, 352.f};
        unsigned int f = 0;
        int r0 = blk * 2;
        for (int rr = 0; rr < 2; rr++) {
            float Y = ((float)(r0 + rr) + 0.5f) * (2.f / UPD) - 1.f;
            float X0 = 0.5f * (2.f / UPD) - 1.f;
            float X1 = 511.5f * (2.f / UPD) - 1.f;
            float gx0 = a10 * X0 + a11 * Y + a12, gy0 = a13 * X0 + a14 * Y + a15;
            float gx1 = a10 * X1 + a11 * Y + a12, gy1 = a13 * X1 + a14 * Y + a15;
            float c0 = 256.f * (a20 * gx0 + a21 * gy0 + a22) + 255.5f;
            float w0 = 256.f * (a23 * gx0 + a24 * gy0 + a25) + 255.5f;
            float c1 = 256.f * (a20 * gx1 + a21 * gy1 + a22) + 255.5f;
            float w1 = 256.f * (a23 * gx1 + a24 * gy1 + a25) + 255.5f;
            float vx = c1 - c0, vy = w1 - w0;
            float vv = fmaxf(vx * vx + vy * vy, 1e-12f);
            for (int j = 0; j < 4; j++) {
                float ux = c0 - ccol[j], uy = w0 - crow[j];
                float tt = fminf(fmaxf(-(ux * vx + uy * vy) / vv, 0.f), 1.f);
                float dx = ux + tt * vx, dy = uy + tt * vy;
                if (dx * dx + dy * dy <= SKIPR * SKIPR) f |= (1u << j);
            }
        }
        sflag = f;
        flags[b * NB + blk] = f;
        if (f == 0) {
#pragma unroll
            for (int j = 0; j < 4; j++) {
                part1[((size_t)(j * BD + b) * NB + blk) * 2 + 0] = 0.f;
                part1[((size_t)(j * BD + b) * NB + blk) * 2 + 1] = 0.f;
            }
        }
    }
    __syncthreads();
    unsigned int f = sflag;

    const float* pr = pred_rot + (size_t)b * (UPD * UPD);
    float* oi = out_img + (size_t)b * (UPD * UPD);
    uchar4* rmb = rm + (size_t)b * (UPD * UPD);
    float s_new[4] = {0.f, 0.f, 0.f, 0.f};
    float s_m[4] = {0.f, 0.f, 0.f, 0.f};
    int base = blk * CHUNK;
    for (int k = 0; k < CHUNK / 256; k++) {
        int p = base + k * 256 + t;
        int yo = p >> 9, xo = p & 511;
        float X = ((float)xo + 0.5f) * (2.f / UPD) - 1.f;
        float Y = ((float)yo + 0.5f) * (2.f / UPD) - 1.f;
        float gx = a10 * X + a11 * Y + a12;
        float gy = a13 * X + a14 * Y + a15;
        float xs = ((gx + 1.f) * (float)UPD - 1.f) * 0.5f;
        float ys = ((gy + 1.f) * (float)UPD - 1.f) * 0.5f;
        float x0f = floorf(xs), y0f = floorf(ys);
        float wx = xs - x0f, wy = ys - y0f;
        int x0 = (int)x0f, y0 = (int)y0f;
        // per-pixel cull via composite affine distance to the 4 disk centers
        bool pact = false;
        if (f) {
            float cxp = 256.f * (a20 * gx + a21 * gy + a22) + 255.5f;
            float cwp = 256.f * (a23 * gx + a24 * gy + a25) + 255.5f;
            const float crow[4] = {160.f, 160.f, 352.f, 352.f};
            const float ccol[4] = {160.f, 352.f, 160.f, 352.f};
#pragma unroll
            for (int j = 0; j < 4; j++) {
                float dx = cxp - ccol[j], dy = cwp - crow[j];
                if (dx * dx + dy * dy <= SKIPR * SKIPR) pact = true;
            }
        }
        float piv = 0.f;
        float m0 = 0.f, m1 = 0.f, m2 = 0.f, m3 = 0.f;
#pragma unroll
        for (int q = 0; q < 4; q++) {
            int qy = y0 + (q >> 1), qx = x0 + (q & 1);
            bool qv = (qx >= 0) && (qx < UPD) && (qy >= 0) && (qy < UPD);
            float fy = (q >> 1) ? wy : (1.f - wy);
            float fx = (q & 1) ? wx : (1.f - wx);
            if (qv) {
                piv += pr[qy * UPD + qx] * fy * fx;
                if (pact) {
                    float Xq = ((float)qx + 0.5f) * (2.f / UPD) - 1.f;
                    float Yq = ((float)qy + 0.5f) * (2.f / UPD) - 1.f;
                    float g2x = a20 * Xq + a21 * Yq + a22;
                    float g2y = a23 * Xq + a24 * Yq + a25;
                    float xs2 = ((g2x + 1.f) * (float)UPD - 1.f) * 0.5f;
                    float ys2 = ((g2y + 1.f) * (float)UPD - 1.f) * 0.5f;
                    float x0f2 = floorf(xs2), y0f2 = floorf(ys2);
                    float wx2 = xs2 - x0f2, wy2 = ys2 - y0f2;
                    int x02 = (int)x0f2, y02 = (int)y0f2;
                    bool vx0 = (x02 >= 0) && (x02 <= UPD - 1);
                    bool vx1 = (x02 + 1 >= 0) && (x02 + 1 <= UPD - 1);
                    bool vy0 = (y02 >= 0) && (y02 <= UPD - 1);
                    bool vy1 = (y02 + 1 >= 0) && (y02 + 1 <= UPD - 1);
                    int xi0 = min(max(x02, 0), UPD - 1);
                    int xi1 = min(max(x02 + 1, 0), UPD - 1);
                    int yi0 = min(max(y02, 0), UPD - 1);
                    int yi1 = min(max(y02 + 1, 0), UPD - 1);
                    float4 c00 = packed[yi0 * UPD + xi0];
                    float4 c01 = packed[yi0 * UPD + xi1];
                    float4 c10 = packed[yi1 * UPD + xi0];
                    float4 c11 = packed[yi1 * UPD + xi1];
                    const float* f00 = (const float*)&c00;
                    const float* f01 = (const float*)&c01;
                    const float* f10 = (const float*)&c10;
                    const float* f11 = (const float*)&c11;
                    float rq[4];
#pragma unroll
                    for (int j = 0; j < 4; j++) {
                        float v00 = (vy0 && vx0) ? f00[j] : 0.f;
                        float v01 = (vy0 && vx1) ? f01[j] : 0.f;
                        float v10 = (vy1 && vx0) ? f10[j] : 0.f;
                        float v11 = (vy1 && vx1) ? f11[j] : 0.f;
                        rq[j] = v00 * (1.f - wy2) * (1.f - wx2) +
                                v01 * (1.f - wy2) * wx2 +
                                v10 * wy2 * (1.f - wx2) + v11 * wy2 * wx2;
                    }
                    m0 += rq[0] * fy * fx;
                    m1 += rq[1] * fy * fx;
                    m2 += rq[2] * fy * fx;
                    m3 += rq[3] * fy * fx;
                }
            }
        }
        oi[p] = piv;
        if (f) {
            uchar4 rmv;
            unsigned char* rmc = (unsigned char*)&rmv;
            float mj[4] = {m0, m1, m2, m3};
#pragma unroll
            for (int j = 0; j < 4; j++) {
                float mm = (mj[j] >= 0.5f) ? 1.f : 0.f;
                rmc[j] = (unsigned char)mm;
                s_new[j] += piv * mm;
                s_m[j] += mm;
            }
            rmb[p] = rmv;
        }
    }
    if (f) {
        __shared__ float r1[256], r2[256];
        for (int j = 0; j < 4; j++) {
            r1[t] = s_new[j];
            r2[t] = s_m[j];
            __syncthreads();
            for (int s = 128; s > 0; s >>= 1) {
                if (t < s) { r1[t] += r1[t + s]; r2[t] += r2[t + s]; }
                __syncthreads();
            }
            if (t == 0) {
                part1[((size_t)(j * BD + b) * NB + blk) * 2 + 0] = r1[0];
                part1[((size_t)(j * BD + b) * NB + blk) * 2 + 1] = r2[0];
            }
            __syncthreads();
        }
    }
}

// All 4 j: thr (redundant reduce of part1) + centroid partials; strip-skip via
// flags; one 4-px uint4 group per thread (streaming, coalesced).
__global__ __launch_bounds__(256) void k_maskB(
        const float* __restrict__ pred_in, const uchar4* __restrict__ rm,
        const float* __restrict__ part1, float* __restrict__ part2,
        const unsigned int* __restrict__ flags) {
    int g = blockIdx.x;
    int b = g & (BD - 1);
    int blk = g >> 4;
    int t = threadIdx.x;
    unsigned int flag = flags[b * NB + blk];
    if (flag == 0) {
        if (t == 0) {
#pragma unroll
            for (int j = 0; j < 4; j++) {
                float* o = part2 + ((size_t)(j * BD + b) * NB + blk) * 4;
                o[0] = 0.f; o[1] = 0.f; o[2] = 0.f;
            }
        }
        return;
    }
    __shared__ float r1[256], r2[256], r3[256];
    float thr[4];
    for (int j = 0; j < 4; j++) {
        r1[t] = part1[((size_t)(j * BD + b) * NB + t) * 2 + 0];
        r2[t] = part1[((size_t)(j * BD + b) * NB + t) * 2 + 1];
        __syncthreads();
        for (int s = 128; s > 0; s >>= 1) {
            if (t < s) { r1[t] += r1[t + s]; r2[t] += r2[t + s]; }
            __syncthreads();
        }
        thr[j] = COEFF * (r1[0] / fmaxf(r2[0], 1.f));
        __syncthreads();
    }
    float tot[4] = {0.f, 0.f, 0.f, 0.f};
    float sx[4] = {0.f, 0.f, 0.f, 0.f};
    float sy[4] = {0.f, 0.f, 0.f, 0.f};
    const float* pi = pred_in + (size_t)b * (UPD * UPD);
    const uchar4* rmb = rm + (size_t)b * (UPD * UPD);
    int p0 = blk * CHUNK + t * 4;
    uint4 mw = *(const uint4*)(rmb + p0);
    if ((mw.x | mw.y | mw.z | mw.w) != 0) {
        float4 pv4 = *(const float4*)(pi + p0);
        const float* pvp = (const float*)&pv4;
        unsigned int mwa[4] = {mw.x, mw.y, mw.z, mw.w};
#pragma unroll
        for (int u = 0; u < 4; u++) {
            if (mwa[u] == 0) continue;
            int p = p0 + u;
            float piv = pvp[u];
            float fi = (float)(p >> 9), fj = (float)(p & 511);
            const unsigned char* mmc = (const unsigned char*)&mwa[u];
#pragma unroll
            for (int j = 0; j < 4; j++) {
                float mm = (float)mmc[j];
                float ni = piv * mm;
                bool sel = (mm > 0.f) && (ni > thr[j]);
                float w = sel ? ni : 0.f;
                tot[j] += w;
                sx[j] += w * fi;
                sy[j] += w * fj;
            }
        }
    }
    for (int j = 0; j < 4; j++) {
        r1[t] = tot[j]; r2[t] = sx[j]; r3[t] = sy[j];
        __syncthreads();
        for (int s = 128; s > 0; s >>= 1) {
            if (t < s) { r1[t] += r1[t + s]; r2[t] += r2[t + s]; r3[t] += r3[t + s]; }
            __syncthreads();
        }
        if (t == 0) {
            float* o = part2 + ((size_t)(j * BD + b) * NB + blk) * 4;
            o[0] = r1[0]; o[1] = r2[0]; o[2] = r3[0];
        }
        __syncthreads();
    }
}

// shared centroid finalize (redundant deterministic reduce per block)
#define CENT_REDUCE(part2, b, t, cs)                                             \
    {                                                                            \
        __shared__ float r1[256], r2[256], r3[256];                              \
        for (int j = 0; j < 4; j++) {                                            \
            if (t < 256) {                                                       \
                const float* pp2 = part2 + ((size_t)(j * BD + b) * NB + t) * 4;  \
                r1[t] = pp2[0]; r2[t] = pp2[1]; r3[t] = pp2[2];                  \
            }                                                                    \
            __syncthreads();                                                     \
            for (int s = 128; s > 0; s >>= 1) {                                  \
                if (t < s) {                                                     \
                    r1[t] += r1[t + s]; r2[t] += r2[t + s]; r3[t] += r3[t + s];  \
                }                                                                \
                __syncthreads();                                                 \
            }                                                                    \
            if (t == 0) {                                                        \
                float tot_ = r1[0] + 1e-8f;                                      \
                float cx_ = r2[0] / tot_;                                        \
                float cy_ = r3[0] / tot_;                                        \
                cs[j * 2 + 0] =                                                  \
                    (int)fminf(fmaxf(rintf(cx_), (float)RAD), (float)(UPD - RAD));\
                cs[j * 2 + 1] =                                                  \
                    (int)fminf(fmaxf(rintf(cy_), (float)RAD), (float)(UPD - RAD));\
            }                                                                    \
            __syncthreads();                                                     \
        }                                                                        \
        if (t == 0) {                                                            \
            int ov_ = 0;                                                         \
            for (int a_ = 0; a_ < 4; a_++)                                       \
                for (int c_ = a_ + 1; c_ < 4; c_++) {                            \
                    int dr = cs[a_ * 2] - cs[c_ * 2];                            \
                    int dc = cs[a_ * 2 + 1] - cs[c_ * 2 + 1];                    \
                    if (dr < 0) dr = -dr;                                        \
                    if (dc < 0) dc = -dc;                                        \
                    if (dr < 2 * RAD && dc < 2 * RAD) ov_ = 1;                   \
                }                                                                \
            cs[8] = ov_;                                                         \
        }                                                                        \
        __syncthreads();                                                         \
    }

// 64 blocks = (b, j). Disjoint case: block (b,j) does LDS-staged
// extract -> resample -> write-back on its own (disjoint) region.
// Overlap case: block (b,0) does the exact sequential 4-step path.
__global__ __launch_bounds__(1024) void k_revise(
        const float* __restrict__ part2, const float* __restrict__ invbuf,
        const float* __restrict__ adj, float* __restrict__ img) {
    int b = blockIdx.x >> 2;
    int jown = blockIdx.x & 3;
    int t = threadIdx.x;
    __shared__ int cs[9];
    CENT_REDUCE(part2, b, t, cs);
    const float* th = invbuf + b * 6;  // inv1
    float th0 = th[0], th1v = th[1], th2v = th[2];
    float th3v = th[3], th4v = th[4], th5v = th[5];
    float a = adj[b];
    float* im = img + (size_t)b * (UPD * UPD);
    __shared__ float patch[PATCHD * PATCHD];
    int jlo = jown, jhi = jown + 1;
    if (cs[8]) {
        if (jown != 0) return;
        jlo = 0; jhi = 4;
    }
    for (int j = jlo; j < jhi; j++) {
        int cxi = cs[j * 2 + 0], cyi = cs[j * 2 + 1];
        for (int p = t; p < PATCHD * PATCHD; p += 1024) {
            int i = p / PATCHD, jj = p - i * PATCHD;
            float v = im[(cxi - RAD + i) * UPD + (cyi - RAD + jj)];
            int di = i - RAD, dj = jj - RAD;
            if (di * di + dj * dj <= 100) v /= a;  // _DOT = 10
            patch[p] = v;
        }
        __syncthreads();
        for (int p = t; p < PATCHD * PATCHD; p += 1024) {
            int i = p / PATCHD, jj = p - i * PATCHD;
            float X = ((float)jj + 0.5f) * (2.f / PATCHD) - 1.f;
            float Y = ((float)i + 0.5f) * (2.f / PATCHD) - 1.f;
            float gx = th0 * X + th1v * Y + th2v;
            float gy = th3v * X + th4v * Y + th5v;
            float v = bsample(patch, PATCHD, PATCHD, gx, gy);
            im[(cxi - RAD + i) * UPD + (cyi - RAD + jj)] = v;
        }
        __syncthreads();
    }
}

// ---------------- launch ----------------

extern "C" void kernel_launch(void* const* d_in, const int* in_sizes, int n_in,
                              void* d_out, int out_size, void* d_ws, size_t ws_size,
                              hipStream_t stream) {
    const float* x = (const float*)d_in[0];
    const float* k_out = (const float*)d_in[1];
    const float* W_dec = (const float*)d_in[2];
    const float* ss = (const float*)d_in[3];
    const float* rot = (const float*)d_in[4];
    const float* masks = (const float*)d_in[5];
    const float* adj = (const float*)d_in[6];

    float* out = (float*)d_out;
    const size_t NX = (size_t)BD * H0D * H0D;      // 1,048,576
    const size_t P = (size_t)BD * UPD * UPD;       // 4,194,304
    float* out_x = out;
    float* out_base = out + NX;
    float* out_img = out + NX + P;                 // pred_in lives here (pristine
                                                   // until k_revise patches it)

    float* ws = (float*)d_ws;
    float* slotR = ws;                   // pred_rot              (P floats)
    uchar4* rm = (uchar4*)(ws + P);      // BD*512*512 uchar4     (P bytes)
    float* slotC = ws + 2 * P;           // base (P/4 floats)
    float* invbuf = ws + 2 * P + P / 4;  // 192 floats
    float* part1 = invbuf + 192;                  // 4*16*256*2 floats
    float* part2 = part1 + 4 * BD * NB * 2;       // 4*16*256*4 floats
    unsigned int* flags = (unsigned int*)(part2 + 4 * BD * NB * 4);  // 16*256 uints
    float4* packed = (float4*)((float*)(flags + BD * NB));  // 512*512 float4 = 4MB

    float* inv2 = invbuf + 96;

    // gemm + affine inversions
    k_gemm<<<257, 256, 0, stream>>>(k_out, W_dec, slotC, ss, rot, invbuf);
    // resize || mask-pack || x-copy
    k_stage<<<BD * NB + 2048, 256, 0, stream>>>(slotC, out_base, masks, packed,
                                                x, out_x);
    // pred_rot = sample(base_inp, inv2)
    k_sample<<<BD * NB, 256, 0, stream>>>(out_base, inv2, slotR);
    // pred_in (out_img) + all-4-mask double-sample + stats pass 1, fused
    k_predmask<<<BD * NB, 256, 0, stream>>>(slotR, packed, invbuf, out_img, rm,
                                            part1, flags);
    // all 4 masks: thr + centroid partials
    k_maskB<<<BD * NB, 256, 0, stream>>>(out_img, rm, part1, part2, flags);
    // centroids + revise, parallel over (b, j) with sequential fallback
    k_revise<<<BD * 4, 1024, 0, stream>>>(part2, invbuf, adj, out_img);
}

// Round 12
// 110.291 us; speedup vs baseline: 1.1567x; 1.0309x over previous
//
#include <hip/hip_runtime.h>

#define BD 16
#define EMBD 128
#define H0D 256
#define UPD 512
#define RAD 60
#define PATCHD 120
#define COEFF 1.5f
#define NB 256          // partial-reduction blocks per batch
#define CHUNK 1024      // pixels per partial block (2 rows of 512)
#define SKIPR 32.0f     // 24 (disk) + 8 margin (bilinear/floor reach <= ~3.5)

// ---------------- small helpers ----------------

// branchless: clamped speculative loads + select (identical values; lets the
// compiler issue all 4 loads without divergent branches)
__device__ __forceinline__ float bsample(const float* __restrict__ img, int H, int W,
                                         float gx, float gy) {
    float xs = ((gx + 1.f) * (float)W - 1.f) * 0.5f;
    float ys = ((gy + 1.f) * (float)H - 1.f) * 0.5f;
    float x0f = floorf(xs), y0f = floorf(ys);
    float wx = xs - x0f, wy = ys - y0f;
    int x0 = (int)x0f, y0 = (int)y0f;
    bool vx0 = (x0 >= 0) && (x0 <= W - 1);
    bool vx1 = (x0 + 1 >= 0) && (x0 + 1 <= W - 1);
    bool vy0 = (y0 >= 0) && (y0 <= H - 1);
    bool vy1 = (y0 + 1 >= 0) && (y0 + 1 <= H - 1);
    int xi0 = min(max(x0, 0), W - 1);
    int xi1 = min(max(x0 + 1, 0), W - 1);
    int yi0 = min(max(y0, 0), H - 1);
    int yi1 = min(max(y0 + 1, 0), H - 1);
    float l00 = img[yi0 * W + xi0];
    float l01 = img[yi0 * W + xi1];
    float l10 = img[yi1 * W + xi0];
    float l11 = img[yi1 * W + xi1];
    float v00 = (vy0 && vx0) ? l00 : 0.f;
    float v01 = (vy0 && vx1) ? l01 : 0.f;
    float v10 = (vy1 && vx0) ? l10 : 0.f;
    float v11 = (vy1 && vx1) ? l11 : 0.f;
    return v00 * (1.f - wy) * (1.f - wx) + v01 * (1.f - wy) * wx +
           v10 * wy * (1.f - wx) + v11 * wy * wx;
}

// ---------------- kernels ----------------

// gemm (blocks 0..255) + inversions (256) + mask-pack (257..1280) +
// x-copy (1281..2304) — pack/copy have no dep on gemm, overlap it.
__global__ __launch_bounds__(256) void k_gemm(
        const float* __restrict__ kout, const float* __restrict__ Wd,
        float* __restrict__ base, const float* __restrict__ ss,
        const float* __restrict__ rot, float* __restrict__ invbuf,
        const float* __restrict__ masks, float4* __restrict__ packed,
        const float* __restrict__ x, float* __restrict__ out_x) {
    int g = blockIdx.x;
    int t = threadIdx.x;
    if (g == 256) {
        int b = t;
        if (b < BD) {
            {
                const float* A = ss + b * 6;
                float a = A[0], bb = A[1], c = A[3], d = A[4];
                float det = a * d - bb * c;
                float* o = invbuf + b * 6;
                o[0] = d / det; o[1] = -bb / det; o[2] = 0.f;
                o[3] = -c / det; o[4] = a / det; o[5] = 0.f;
            }
            {
                const float* A = rot + b * 6;
                float a = A[0], bb = A[1], c = A[3], d = A[4];
                float det = a * d - bb * c;
                float* o = invbuf + 96 + b * 6;
                o[0] = d / det; o[1] = -bb / det; o[2] = 0.f;
                o[3] = -c / det; o[4] = a / det; o[5] = 0.f;
            }
        }
        return;
    }
    if (g > 256) {
        if (g < 257 + 1024) {
            int p = (g - 257) * 256 + t;
            float4 v;
            v.x = masks[p];
            v.y = masks[(size_t)(UPD * UPD) + p];
            v.z = masks[(size_t)2 * (UPD * UPD) + p];
            v.w = masks[(size_t)3 * (UPD * UPD) + p];
            packed[p] = v;
        } else {
            int idx = (g - 257 - 1024) * 256 + t;
            ((float4*)out_x)[idx] = ((const float4*)x)[idx];
        }
        return;
    }
    __shared__ float sk[BD * EMBD];
    for (int i = t; i < BD * EMBD; i += 256) sk[i] = kout[i];
    __syncthreads();
    int n = g * 256 + t;
    float acc[BD];
#pragma unroll
    for (int b = 0; b < BD; b++) acc[b] = 0.f;
    for (int e = 0; e < EMBD; e++) {
        float w = Wd[(size_t)e * (H0D * H0D) + n];
#pragma unroll
        for (int b = 0; b < BD; b++) acc[b] += sk[b * EMBD + e] * w;
    }
#pragma unroll
    for (int b = 0; b < BD; b++)
        base[(size_t)b * (H0D * H0D) + n] = fmaxf(acc[b], 0.f);
}

// bilinear resize 256->512, batch-interleaved, 4 px/thread float4 store
__global__ __launch_bounds__(256) void k_resize(const float* __restrict__ base,
                                                float* __restrict__ out) {
    int g = blockIdx.x;
    int b = g & (BD - 1);
    int blk = g >> 4;
    int t = threadIdx.x;
    const float* img = base + (size_t)b * (H0D * H0D);
    float* ob = out + (size_t)b * (UPD * UPD);
    int p0 = blk * CHUNK + t * 4;
    float4 o;
    float* op = (float*)&o;
#pragma unroll
    for (int u = 0; u < 4; u++) {
        int p = p0 + u;
        int yo = p >> 9, xo = p & 511;
        float ysf = fminf(fmaxf(((float)yo + 0.5f) * 0.5f - 0.5f, 0.f), 255.f);
        float xsf = fminf(fmaxf(((float)xo + 0.5f) * 0.5f - 0.5f, 0.f), 255.f);
        int y0 = (int)floorf(ysf), x0 = (int)floorf(xsf);
        int y1 = min(y0 + 1, H0D - 1), x1 = min(x0 + 1, H0D - 1);
        float wy = ysf - (float)y0, wx = xsf - (float)x0;
        float Ia = img[y0 * H0D + x0], Ib = img[y0 * H0D + x1];
        float Ic = img[y1 * H0D + x0], Id = img[y1 * H0D + x1];
        op[u] = Ia * (1.f - wy) * (1.f - wx) + Ib * (1.f - wy) * wx +
                Ic * wy * (1.f - wx) + Id * wy * wx;
    }
    *(float4*)(ob + p0) = o;
}

// affine grid-sample, batch-interleaved, 4 pixels/thread with float4 store
__global__ __launch_bounds__(256) void k_sample(const float* __restrict__ in,
                                                const float* __restrict__ theta,
                                                float* __restrict__ out) {
    int g = blockIdx.x;
    int b = g & (BD - 1);
    int blk = g >> 4;
    int t = threadIdx.x;
    const float* th = theta + b * 6;
    float a0 = th[0], a1 = th[1], a2 = th[2];
    float a3 = th[3], a4 = th[4], a5 = th[5];
    const float* img = in + (size_t)b * (UPD * UPD);
    float* ob = out + (size_t)b * (UPD * UPD);
    int p0 = blk * CHUNK + t * 4;
    float4 o;
    float* op = (float*)&o;
#pragma unroll
    for (int u = 0; u < 4; u++) {
        int p = p0 + u;
        int yo = p >> 9, xo = p & 511;
        float X = ((float)xo + 0.5f) * (2.f / UPD) - 1.f;
        float Y = ((float)yo + 0.5f) * (2.f / UPD) - 1.f;
        float gx = a0 * X + a1 * Y + a2;
        float gy = a3 * X + a4 * Y + a5;
        op[u] = bsample(img, UPD, UPD, gx, gy);
    }
    *(float4*)(ob + p0) = o;
}

// FUSED: pred_in = sample(pred_rot, inv1) written to out_img, PLUS
// rm_j = (sample(sample(mask_j, inv2), inv1) >= 0.5) + stats pass 1.
// Strip-skip + per-pixel cull; pred gather is branchless speculative.
__global__ __launch_bounds__(256) void k_predmask(
        const float* __restrict__ pred_rot, const float4* __restrict__ packed,
        const float* __restrict__ invbuf, float* __restrict__ out_img,
        uchar4* __restrict__ rm, float* __restrict__ part1,
        unsigned int* __restrict__ flags) {
    int g = blockIdx.x;
    int b = g & (BD - 1);
    int blk = g >> 4;
    int t = threadIdx.x;
    const float* th1 = invbuf + b * 6;        // outer (inv1)
    const float* th2 = invbuf + 96 + b * 6;   // inner (inv2)
    float a10 = th1[0], a11 = th1[1], a12 = th1[2];
    float a13 = th1[3], a14 = th1[4], a15 = th1[5];
    float a20 = th2[0], a21 = th2[1], a22 = th2[2];
    float a23 = th2[3], a24 = th2[4], a25 = th2[5];

    __shared__ unsigned int sflag;
    if (t == 0) {
        const float crow[4] = {160.f, 160.f, 352.f, 352.f};
        const float ccol[4] = {160.f, 352.f, 160.f, 352.f};
        unsigned int f = 0;
        int r0 = blk * 2;
        for (int rr = 0; rr < 2; rr++) {
            float Y = ((float)(r0 + rr) + 0.5f) * (2.f / UPD) - 1.f;
            float X0 = 0.5f * (2.f / UPD) - 1.f;
            float X1 = 511.5f * (2.f / UPD) - 1.f;
            float gx0 = a10 * X0 + a11 * Y + a12, gy0 = a13 * X0 + a14 * Y + a15;
            float gx1 = a10 * X1 + a11 * Y + a12, gy1 = a13 * X1 + a14 * Y + a15;
            float c0 = 256.f * (a20 * gx0 + a21 * gy0 + a22) + 255.5f;
            float w0 = 256.f * (a23 * gx0 + a24 * gy0 + a25) + 255.5f;
            float c1 = 256.f * (a20 * gx1 + a21 * gy1 + a22) + 255.5f;
            float w1 = 256.f * (a23 * gx1 + a24 * gy1 + a25) + 255.5f;
            float vx = c1 - c0, vy = w1 - w0;
            float vv = fmaxf(vx * vx + vy * vy, 1e-12f);
            for (int j = 0; j < 4; j++) {
                float ux = c0 - ccol[j], uy = w0 - crow[j];
                float tt = fminf(fmaxf(-(ux * vx + uy * vy) / vv, 0.f), 1.f);
                float dx = ux + tt * vx, dy = uy + tt * vy;
                if (dx * dx + dy * dy <= SKIPR * SKIPR) f |= (1u << j);
            }
        }
        sflag = f;
        flags[b * NB + blk] = f;
        if (f == 0) {
#pragma unroll
            for (int j = 0; j < 4; j++) {
                part1[((size_t)(j * BD + b) * NB + blk) * 2 + 0] = 0.f;
                part1[((size_t)(j * BD + b) * NB + blk) * 2 + 1] = 0.f;
            }
        }
    }
    __syncthreads();
    unsigned int f = sflag;

    const float* pr = pred_rot + (size_t)b * (UPD * UPD);
    float* oi = out_img + (size_t)b * (UPD * UPD);
    uchar4* rmb = rm + (size_t)b * (UPD * UPD);
    float s_new[4] = {0.f, 0.f, 0.f, 0.f};
    float s_m[4] = {0.f, 0.f, 0.f, 0.f};
    int base = blk * CHUNK;
    for (int k = 0; k < CHUNK / 256; k++) {
        int p = base + k * 256 + t;
        int yo = p >> 9, xo = p & 511;
        float X = ((float)xo + 0.5f) * (2.f / UPD) - 1.f;
        float Y = ((float)yo + 0.5f) * (2.f / UPD) - 1.f;
        float gx = a10 * X + a11 * Y + a12;
        float gy = a13 * X + a14 * Y + a15;
        float xs = ((gx + 1.f) * (float)UPD - 1.f) * 0.5f;
        float ys = ((gy + 1.f) * (float)UPD - 1.f) * 0.5f;
        float x0f = floorf(xs), y0f = floorf(ys);
        float wx = xs - x0f, wy = ys - y0f;
        int x0 = (int)x0f, y0 = (int)y0f;
        // per-pixel cull via composite affine distance to the 4 disk centers
        bool pact = false;
        if (f) {
            float cxp = 256.f * (a20 * gx + a21 * gy + a22) + 255.5f;
            float cwp = 256.f * (a23 * gx + a24 * gy + a25) + 255.5f;
            const float crow[4] = {160.f, 160.f, 352.f, 352.f};
            const float ccol[4] = {160.f, 352.f, 160.f, 352.f};
#pragma unroll
            for (int j = 0; j < 4; j++) {
                float dx = cxp - ccol[j], dy = cwp - crow[j];
                if (dx * dx + dy * dy <= SKIPR * SKIPR) pact = true;
            }
        }
        // branchless speculative pred gather
        bool vx0 = (x0 >= 0) && (x0 <= UPD - 1);
        bool vx1 = (x0 + 1 >= 0) && (x0 + 1 <= UPD - 1);
        bool vy0 = (y0 >= 0) && (y0 <= UPD - 1);
        bool vy1 = (y0 + 1 >= 0) && (y0 + 1 <= UPD - 1);
        int xi0 = min(max(x0, 0), UPD - 1);
        int xi1 = min(max(x0 + 1, 0), UPD - 1);
        int yi0 = min(max(y0, 0), UPD - 1);
        int yi1 = min(max(y0 + 1, 0), UPD - 1);
        float l00 = pr[yi0 * UPD + xi0];
        float l01 = pr[yi0 * UPD + xi1];
        float l10 = pr[yi1 * UPD + xi0];
        float l11 = pr[yi1 * UPD + xi1];
        float p00 = (vy0 && vx0) ? l00 : 0.f;
        float p01 = (vy0 && vx1) ? l01 : 0.f;
        float p10 = (vy1 && vx0) ? l10 : 0.f;
        float p11 = (vy1 && vx1) ? l11 : 0.f;
        float piv = p00 * (1.f - wy) * (1.f - wx) + p01 * (1.f - wy) * wx +
                    p10 * wy * (1.f - wx) + p11 * wy * wx;
        float m0 = 0.f, m1 = 0.f, m2 = 0.f, m3 = 0.f;
        if (pact) {
#pragma unroll
            for (int q = 0; q < 4; q++) {
                int qy = y0 + (q >> 1), qx = x0 + (q & 1);
                bool qv = (qx >= 0) && (qx < UPD) && (qy >= 0) && (qy < UPD);
                float fy = (q >> 1) ? wy : (1.f - wy);
                float fx = (q & 1) ? wx : (1.f - wx);
                if (qv) {
                    float Xq = ((float)qx + 0.5f) * (2.f / UPD) - 1.f;
                    float Yq = ((float)qy + 0.5f) * (2.f / UPD) - 1.f;
                    float g2x = a20 * Xq + a21 * Yq + a22;
                    float g2y = a23 * Xq + a24 * Yq + a25;
                    float xs2 = ((g2x + 1.f) * (float)UPD - 1.f) * 0.5f;
                    float ys2 = ((g2y + 1.f) * (float)UPD - 1.f) * 0.5f;
                    float x0f2 = floorf(xs2), y0f2 = floorf(ys2);
                    float wx2 = xs2 - x0f2, wy2 = ys2 - y0f2;
                    int x02 = (int)x0f2, y02 = (int)y0f2;
                    bool wx0v = (x02 >= 0) && (x02 <= UPD - 1);
                    bool wx1v = (x02 + 1 >= 0) && (x02 + 1 <= UPD - 1);
                    bool wy0v = (y02 >= 0) && (y02 <= UPD - 1);
                    bool wy1v = (y02 + 1 >= 0) && (y02 + 1 <= UPD - 1);
                    int mxi0 = min(max(x02, 0), UPD - 1);
                    int mxi1 = min(max(x02 + 1, 0), UPD - 1);
                    int myi0 = min(max(y02, 0), UPD - 1);
                    int myi1 = min(max(y02 + 1, 0), UPD - 1);
                    float4 c00 = packed[myi0 * UPD + mxi0];
                    float4 c01 = packed[myi0 * UPD + mxi1];
                    float4 c10 = packed[myi1 * UPD + mxi0];
                    float4 c11 = packed[myi1 * UPD + mxi1];
                    const float* f00 = (const float*)&c00;
                    const float* f01 = (const float*)&c01;
                    const float* f10 = (const float*)&c10;
                    const float* f11 = (const float*)&c11;
                    float rq[4];
#pragma unroll
                    for (int j = 0; j < 4; j++) {
                        float v00 = (wy0v && wx0v) ? f00[j] : 0.f;
                        float v01 = (wy0v && wx1v) ? f01[j] : 0.f;
                        float v10 = (wy1v && wx0v) ? f10[j] : 0.f;
                        float v11 = (wy1v && wx1v) ? f11[j] : 0.f;
                        rq[j] = v00 * (1.f - wy2) * (1.f - wx2) +
                                v01 * (1.f - wy2) * wx2 +
                                v10 * wy2 * (1.f - wx2) + v11 * wy2 * wx2;
                    }
                    m0 += rq[0] * fy * fx;
                    m1 += rq[1] * fy * fx;
                    m2 += rq[2] * fy * fx;
                    m3 += rq[3] * fy * fx;
                }
            }
        }
        oi[p] = piv;
        if (f) {
            uchar4 rmv;
            unsigned char* rmc = (unsigned char*)&rmv;
            float mj[4] = {m0, m1, m2, m3};
#pragma unroll
            for (int j = 0; j < 4; j++) {
                float mm = (mj[j] >= 0.5f) ? 1.f : 0.f;
                rmc[j] = (unsigned char)mm;
                s_new[j] += piv * mm;
                s_m[j] += mm;
            }
            rmb[p] = rmv;
        }
    }
    if (f) {
        __shared__ float r1[256], r2[256];
        for (int j = 0; j < 4; j++) {
            r1[t] = s_new[j];
            r2[t] = s_m[j];
            __syncthreads();
            for (int s = 128; s > 0; s >>= 1) {
                if (t < s) { r1[t] += r1[t + s]; r2[t] += r2[t + s]; }
                __syncthreads();
            }
            if (t == 0) {
                part1[((size_t)(j * BD + b) * NB + blk) * 2 + 0] = r1[0];
                part1[((size_t)(j * BD + b) * NB + blk) * 2 + 1] = r2[0];
            }
            __syncthreads();
        }
    }
}

// All 4 j: thr (redundant reduce of part1) + centroid partials; strip-skip via
// flags; one 4-px uint4 group per thread (streaming, coalesced).
__global__ __launch_bounds__(256) void k_maskB(
        const float* __restrict__ pred_in, const uchar4* __restrict__ rm,
        const float* __restrict__ part1, float* __restrict__ part2,
        const unsigned int* __restrict__ flags) {
    int g = blockIdx.x;
    int b = g & (BD - 1);
    int blk = g >> 4;
    int t = threadIdx.x;
    unsigned int flag = flags[b * NB + blk];
    if (flag == 0) {
        if (t == 0) {
#pragma unroll
            for (int j = 0; j < 4; j++) {
                float* o = part2 + ((size_t)(j * BD + b) * NB + blk) * 4;
                o[0] = 0.f; o[1] = 0.f; o[2] = 0.f;
            }
        }
        return;
    }
    __shared__ float r1[256], r2[256], r3[256];
    float thr[4];
    for (int j = 0; j < 4; j++) {
        r1[t] = part1[((size_t)(j * BD + b) * NB + t) * 2 + 0];
        r2[t] = part1[((size_t)(j * BD + b) * NB + t) * 2 + 1];
        __syncthreads();
        for (int s = 128; s > 0; s >>= 1) {
            if (t < s) { r1[t] += r1[t + s]; r2[t] += r2[t + s]; }
            __syncthreads();
        }
        thr[j] = COEFF * (r1[0] / fmaxf(r2[0], 1.f));
        __syncthreads();
    }
    float tot[4] = {0.f, 0.f, 0.f, 0.f};
    float sx[4] = {0.f, 0.f, 0.f, 0.f};
    float sy[4] = {0.f, 0.f, 0.f, 0.f};
    const float* pi = pred_in + (size_t)b * (UPD * UPD);
    const uchar4* rmb = rm + (size_t)b * (UPD * UPD);
    int p0 = blk * CHUNK + t * 4;
    uint4 mw = *(const uint4*)(rmb + p0);
    if ((mw.x | mw.y | mw.z | mw.w) != 0) {
        float4 pv4 = *(const float4*)(pi + p0);
        const float* pvp = (const float*)&pv4;
        unsigned int mwa[4] = {mw.x, mw.y, mw.z, mw.w};
#pragma unroll
        for (int u = 0; u < 4; u++) {
            if (mwa[u] == 0) continue;
            int p = p0 + u;
            float piv = pvp[u];
            float fi = (float)(p >> 9), fj = (float)(p & 511);
            const unsigned char* mmc = (const unsigned char*)&mwa[u];
#pragma unroll
            for (int j = 0; j < 4; j++) {
                float mm = (float)mmc[j];
                float ni = piv * mm;
                bool sel = (mm > 0.f) && (ni > thr[j]);
                float w = sel ? ni : 0.f;
                tot[j] += w;
                sx[j] += w * fi;
                sy[j] += w * fj;
            }
        }
    }
    for (int j = 0; j < 4; j++) {
        r1[t] = tot[j]; r2[t] = sx[j]; r3[t] = sy[j];
        __syncthreads();
        for (int s = 128; s > 0; s >>= 1) {
            if (t < s) { r1[t] += r1[t + s]; r2[t] += r2[t + s]; r3[t] += r3[t + s]; }
            __syncthreads();
        }
        if (t == 0) {
            float* o = part2 + ((size_t)(j * BD + b) * NB + blk) * 4;
            o[0] = r1[0]; o[1] = r2[0]; o[2] = r3[0];
        }
        __syncthreads();
    }
}

// shared centroid finalize (redundant deterministic reduce per block)
#define CENT_REDUCE(part2, b, t, cs)                                             \
    {                                                                            \
        __shared__ float r1[256], r2[256], r3[256];                              \
        for (int j = 0; j < 4; j++) {                                            \
            if (t < 256) {                                                       \
                const float* pp2 = part2 + ((size_t)(j * BD + b) * NB + t) * 4;  \
                r1[t] = pp2[0]; r2[t] = pp2[1]; r3[t] = pp2[2];                  \
            }                                                                    \
            __syncthreads();                                                     \
            for (int s = 128; s > 0; s >>= 1) {                                  \
                if (t < s) {                                                     \
                    r1[t] += r1[t + s]; r2[t] += r2[t + s]; r3[t] += r3[t + s];  \
                }                                                                \
                __syncthreads();                                                 \
            }                                                                    \
            if (t == 0) {                                                        \
                float tot_ = r1[0] + 1e-8f;                                      \
                float cx_ = r2[0] / tot_;                                        \
                float cy_ = r3[0] / tot_;                                        \
                cs[j * 2 + 0] =                                                  \
                    (int)fminf(fmaxf(rintf(cx_), (float)RAD), (float)(UPD - RAD));\
                cs[j * 2 + 1] =                                                  \
                    (int)fminf(fmaxf(rintf(cy_), (float)RAD), (float)(UPD - RAD));\
            }                                                                    \
            __syncthreads();                                                     \
        }                                                                        \
        if (t == 0) {                                                            \
            int ov_ = 0;                                                         \
            for (int a_ = 0; a_ < 4; a_++)                                       \
                for (int c_ = a_ + 1; c_ < 4; c_++) {                            \
                    int dr = cs[a_ * 2] - cs[c_ * 2];                            \
                    int dc = cs[a_ * 2 + 1] - cs[c_ * 2 + 1];                    \
                    if (dr < 0) dr = -dr;                                        \
                    if (dc < 0) dc = -dc;                                        \
                    if (dr < 2 * RAD && dc < 2 * RAD) ov_ = 1;                   \
                }                                                                \
            cs[8] = ov_;                                                         \
        }                                                                        \
        __syncthreads();                                                         \
    }

// 64 blocks = (b, j). Disjoint case: block (b,j) does LDS-staged
// extract -> resample -> write-back on its own (disjoint) region.
// Overlap case: block (b,0) does the exact sequential 4-step path.
__global__ __launch_bounds__(1024) void k_revise(
        const float* __restrict__ part2, const float* __restrict__ invbuf,
        const float* __restrict__ adj, float* __restrict__ img) {
    int b = blockIdx.x >> 2;
    int jown = blockIdx.x & 3;
    int t = threadIdx.x;
    __shared__ int cs[9];
    CENT_REDUCE(part2, b, t, cs);
    const float* th = invbuf + b * 6;  // inv1
    float th0 = th[0], th1v = th[1], th2v = th[2];
    float th3v = th[3], th4v = th[4], th5v = th[5];
    float a = adj[b];
    float* im = img + (size_t)b * (UPD * UPD);
    __shared__ float patch[PATCHD * PATCHD];
    int jlo = jown, jhi = jown + 1;
    if (cs[8]) {
        if (jown != 0) return;
        jlo = 0; jhi = 4;
    }
    for (int j = jlo; j < jhi; j++) {
        int cxi = cs[j * 2 + 0], cyi = cs[j * 2 + 1];
        for (int p = t; p < PATCHD * PATCHD; p += 1024) {
            int i = p / PATCHD, jj = p - i * PATCHD;
            float v = im[(cxi - RAD + i) * UPD + (cyi - RAD + jj)];
            int di = i - RAD, dj = jj - RAD;
            if (di * di + dj * dj <= 100) v /= a;  // _DOT = 10
            patch[p] = v;
        }
        __syncthreads();
        for (int p = t; p < PATCHD * PATCHD; p += 1024) {
            int i = p / PATCHD, jj = p - i * PATCHD;
            float X = ((float)jj + 0.5f) * (2.f / PATCHD) - 1.f;
            float Y = ((float)i + 0.5f) * (2.f / PATCHD) - 1.f;
            float gx = th0 * X + th1v * Y + th2v;
            float gy = th3v * X + th4v * Y + th5v;
            float v = bsample(patch, PATCHD, PATCHD, gx, gy);
            im[(cxi - RAD + i) * UPD + (cyi - RAD + jj)] = v;
        }
        __syncthreads();
    }
}

// ---------------- launch ----------------

extern "C" void kernel_launch(void* const* d_in, const int* in_sizes, int n_in,
                              void* d_out, int out_size, void* d_ws, size_t ws_size,
                              hipStream_t stream) {
    const float* x = (const float*)d_in[0];
    const float* k_out = (const float*)d_in[1];
    const float* W_dec = (const float*)d_in[2];
    const float* ss = (const float*)d_in[3];
    const float* rot = (const float*)d_in[4];
    const float* masks = (const float*)d_in[5];
    const float* adj = (const float*)d_in[6];

    float* out = (float*)d_out;
    const size_t NX = (size_t)BD * H0D * H0D;      // 1,048,576
    const size_t P = (size_t)BD * UPD * UPD;       // 4,194,304
    float* out_x = out;
    float* out_base = out + NX;
    float* out_img = out + NX + P;                 // pred_in lives here (pristine
                                                   // until k_revise patches it)

    float* ws = (float*)d_ws;
    float* slotR = ws;                   // pred_rot              (P floats)
    uchar4* rm = (uchar4*)(ws + P);      // BD*512*512 uchar4     (P bytes)
    float* slotC = ws + 2 * P;           // base (P/4 floats)
    float* invbuf = ws + 2 * P + P / 4;  // 192 floats
    float* part1 = invbuf + 192;                  // 4*16*256*2 floats
    float* part2 = part1 + 4 * BD * NB * 2;       // 4*16*256*4 floats
    unsigned int* flags = (unsigned int*)(part2 + 4 * BD * NB * 4);  // 16*256 uints
    float4* packed = (float4*)((float*)(flags + BD * NB));  // 512*512 float4 = 4MB

    float* inv2 = invbuf + 96;

    // gemm + inversions + mask-pack + x-copy (pack/copy overlap gemm)
    k_gemm<<<257 + 2048, 256, 0, stream>>>(k_out, W_dec, slotC, ss, rot, invbuf,
                                           masks, packed, x, out_x);
    // resize only
    k_resize<<<BD * NB, 256, 0, stream>>>(slotC, out_base);
    // pred_rot = sample(base_inp, inv2)
    k_sample<<<BD * NB, 256, 0, stream>>>(out_base, inv2, slotR);
    // pred_in (out_img) + all-4-mask double-sample + stats pass 1, fused
    k_predmask<<<BD * NB, 256, 0, stream>>>(slotR, packed, invbuf, out_img, rm,
                                            part1, flags);
    // all 4 masks: thr + centroid partials
    k_maskB<<<BD * NB, 256, 0, stream>>>(out_img, rm, part1, part2, flags);
    // centroids + revise, parallel over (b, j) with sequential fallback
    k_revise<<<BD * 4, 1024, 0, stream>>>(part2, invbuf, adj, out_img);
}